// Round 5
// baseline (235.071 us; speedup 1.0000x reference)
//
#include <hip/hip_runtime.h>

typedef short bf16x8 __attribute__((ext_vector_type(8)));
typedef float f32x4 __attribute__((ext_vector_type(4)));
typedef unsigned short u16x8 __attribute__((ext_vector_type(8)));

static __device__ __forceinline__ unsigned short f2bf(float f) {
  unsigned int x = __builtin_bit_cast(unsigned int, f);
  x += 0x7FFFu + ((x >> 16) & 1u);   // RNE
  return (unsigned short)(x >> 16);
}
// pack two floats' bf16 (round-half-up) into one u32 (lo=a, hi=b)
static __device__ __forceinline__ unsigned int pk2bf(float a, float b) {
  unsigned int ia = __builtin_bit_cast(unsigned int, a) + 0x8000u;
  unsigned int ib = __builtin_bit_cast(unsigned int, b) + 0x8000u;
  return __builtin_amdgcn_perm(ib, ia, 0x07060302u);
}
// async 16B global -> LDS
static __device__ __forceinline__ void gl2lds16(const unsigned short* g, unsigned short* l) {
  __builtin_amdgcn_global_load_lds(
      (const __attribute__((address_space(1))) unsigned int*)g,
      (__attribute__((address_space(3))) unsigned int*)l, 16, 0, 0);
}

// ---- q/k/v fp32 -> packed xbf[8192][1536] bf16 (8 elems/thread) ----
__global__ __launch_bounds__(256) void cvt3(const float* __restrict__ q, const float* __restrict__ k,
                                            const float* __restrict__ v,
                                            unsigned short* __restrict__ xbf) {
  const int sec = blockIdx.y;
  const float* src = (sec == 0) ? q : (sec == 1) ? k : v;
  int i = (blockIdx.x * 256 + threadIdx.x) * 8;     // over 8192*512
  int row = i >> 9, col = i & 511;
  float4 a = *(const float4*)(src + i);
  float4 b = *(const float4*)(src + i + 4);
  uint4 pk;
  pk.x = pk2bf(a.x, a.y); pk.y = pk2bf(a.z, a.w);
  pk.z = pk2bf(b.x, b.y); pk.w = pk2bf(b.z, b.w);
  *(uint4*)(xbf + (size_t)row * 1536 + sec * 512 + col) = pk;
}

// ------- 4x W [512k][512n] f32 -> WT [4][512n][512k] bf16 (z selects matrix) -------
__global__ __launch_bounds__(256) void wtrans4(const float* __restrict__ Wq, const float* __restrict__ Wk,
                                               const float* __restrict__ Wv, const float* __restrict__ Wo,
                                               unsigned short* __restrict__ WT) {
  __shared__ __align__(16) float T[64 * 68];
  const int z = blockIdx.z;
  const float* W = (z == 0) ? Wq : (z == 1) ? Wk : (z == 2) ? Wv : Wo;
  unsigned short* out = WT + (size_t)z * 512 * 512;
  const int k0 = blockIdx.x * 64, n0 = blockIdx.y * 64;
  const int tid = threadIdx.x;
#pragma unroll
  for (int i = 0; i < 4; ++i) {
    int chunk = i * 256 + tid;
    int row = chunk >> 4, fc = chunk & 15;
    *(float4*)(T + row * 68 + fc * 4) =
        *(const float4*)(W + (size_t)(k0 + row) * 512 + n0 + fc * 4);
  }
  __syncthreads();
#pragma unroll
  for (int i = 0; i < 2; ++i) {
    int chunk = i * 256 + tid;
    int nr = chunk >> 3, kc = chunk & 7;
    u16x8 v;
#pragma unroll
    for (int j = 0; j < 8; ++j) v[j] = f2bf(T[(kc * 8 + j) * 68 + nr]);
    *(u16x8*)(out + (size_t)(n0 + nr) * 512 + k0 + kc * 8) = v;
  }
}

// ---- fused QKV GEMM: C[8192][1536]. 128x128 tile, BK=32, 4x4 acc/wave, async dbuf. ----
__global__ __launch_bounds__(256) void gemm_qkv(const unsigned short* __restrict__ xbf,
                                                const unsigned short* __restrict__ Bt,
                                                unsigned short* __restrict__ C,
                                                float qscale) {
  __shared__ __align__(16) unsigned short Abuf[2][128 * 32];
  __shared__ __align__(16) unsigned short Bbuf[2][128 * 32];
  const int by = blockIdx.y;
  const unsigned short* A = xbf + (by >> 2) * 512;      // q/k/v section of packed input
  const float scale = (by < 4) ? qscale : 1.0f;
  const int tid = threadIdx.x;
  const int wid = tid >> 6, lane = tid & 63, quad = lane >> 4, li = lane & 15;
  const int bm = blockIdx.x * 128, bn = by * 128;
  const int wm = (wid & 1) * 64, wn = (wid >> 1) * 64;
  const unsigned short* ga[2]; int oa[2];
  const unsigned short* gb[2]; int obx[2];
#pragma unroll
  for (int i = 0; i < 2; ++i) {
    int lam = i * 256 + tid;                 // [0,512) chunk id
    int r = lam >> 2, c = (lam & 3) ^ (r & 3);
    ga[i] = A + (size_t)(bm + r) * 1536 + c * 8;
    oa[i] = lam * 8;
    gb[i] = Bt + (size_t)(bn + r) * 512 + c * 8;
    obx[i] = lam * 8;
  }
#pragma unroll
  for (int i = 0; i < 2; ++i) {
    gl2lds16(ga[i], &Abuf[0][oa[i]]); ga[i] += 32;
    gl2lds16(gb[i], &Bbuf[0][obx[i]]); gb[i] += 32;
  }
  f32x4 acc[4][4] = {};
  const int sw = li & 3;
  for (int s = 0; s < 16; ++s) {
    __syncthreads();
    if (s + 1 < 16) {
      int p = (s + 1) & 1;
#pragma unroll
      for (int i = 0; i < 2; ++i) {
        gl2lds16(ga[i], &Abuf[p][oa[i]]); ga[i] += 32;
        gl2lds16(gb[i], &Bbuf[p][obx[i]]); gb[i] += 32;
      }
    }
    const unsigned short* As = &Abuf[s & 1][0];
    const unsigned short* Bs = &Bbuf[s & 1][0];
    bf16x8 af[4], bfr[4];
#pragma unroll
    for (int t = 0; t < 4; ++t) {
      af[t]  = *(const bf16x8*)(As + (wm + t * 16 + li) * 32 + ((quad ^ sw) * 8));
      bfr[t] = *(const bf16x8*)(Bs + (wn + t * 16 + li) * 32 + ((quad ^ sw) * 8));
    }
#pragma unroll
    for (int mt = 0; mt < 4; ++mt)
#pragma unroll
      for (int nt = 0; nt < 4; ++nt)
        acc[mt][nt] = __builtin_amdgcn_mfma_f32_16x16x32_bf16(af[mt], bfr[nt], acc[mt][nt], 0, 0, 0);
  }
#pragma unroll
  for (int mt = 0; mt < 4; ++mt)
#pragma unroll
    for (int nt = 0; nt < 4; ++nt) {
      int r0 = bm + wm + mt * 16 + quad * 4;
      int c  = bn + wn + nt * 16 + li;
#pragma unroll
      for (int r = 0; r < 4; ++r)
        C[(size_t)(r0 + r) * 1536 + c] = f2bf(acc[mt][nt][r] * scale);
    }
}

// ---- O-proj GEMM: out[8192][512] f32 = ob[8192][512] * woT^T. 128x64, BK=64, dbuf. ----
__global__ __launch_bounds__(256) void gemm_o(const unsigned short* __restrict__ A,
                                              const unsigned short* __restrict__ Bt,
                                              float* __restrict__ Cf) {
  __shared__ __align__(16) unsigned short Abuf[2][128 * 64];
  __shared__ __align__(16) unsigned short Bbuf[2][64 * 64];
  const int K = 512, LDC = 512;
  const int tid = threadIdx.x;
  const int wid = tid >> 6, lane = tid & 63, quad = lane >> 4, li = lane & 15;
  const int bm = blockIdx.x * 128, bn = blockIdx.y * 64;
  const int wm = wid * 32;
  const unsigned short* ga[4]; int oa[4];
  const unsigned short* gb[2]; int ob[2];
#pragma unroll
  for (int i = 0; i < 4; ++i) {
    int lam = i * 256 + wid * 64 + lane;
    int r = lam >> 3, c = (lam & 7) ^ (r & 7);
    ga[i] = A + (size_t)(bm + r) * K + c * 8;
    oa[i] = lam * 8;
  }
#pragma unroll
  for (int i = 0; i < 2; ++i) {
    int lam = i * 256 + wid * 64 + lane;
    int r = lam >> 3, c = (lam & 7) ^ (r & 7);
    gb[i] = Bt + (size_t)(bn + r) * K + c * 8;
    ob[i] = lam * 8;
  }
#pragma unroll
  for (int i = 0; i < 4; ++i) { gl2lds16(ga[i], &Abuf[0][oa[i]]); ga[i] += 64; }
#pragma unroll
  for (int i = 0; i < 2; ++i) { gl2lds16(gb[i], &Bbuf[0][ob[i]]); gb[i] += 64; }

  f32x4 acc[2][4] = {};
  const int sw = li & 7;
  for (int s = 0; s < 8; ++s) {
    __syncthreads();
    if (s + 1 < 8) {
      int p = (s + 1) & 1;
#pragma unroll
      for (int i = 0; i < 4; ++i) { gl2lds16(ga[i], &Abuf[p][oa[i]]); ga[i] += 64; }
#pragma unroll
      for (int i = 0; i < 2; ++i) { gl2lds16(gb[i], &Bbuf[p][ob[i]]); gb[i] += 64; }
    }
    const unsigned short* As = &Abuf[s & 1][0];
    const unsigned short* Bs = &Bbuf[s & 1][0];
#pragma unroll
    for (int kk = 0; kk < 2; ++kk) {
      bf16x8 af[2], bfr[4];
#pragma unroll
      for (int t = 0; t < 2; ++t)
        af[t] = *(const bf16x8*)(As + (wm + t * 16 + li) * 64 + (((kk * 4 + quad) ^ sw) * 8));
#pragma unroll
      for (int t = 0; t < 4; ++t)
        bfr[t] = *(const bf16x8*)(Bs + (t * 16 + li) * 64 + (((kk * 4 + quad) ^ sw) * 8));
#pragma unroll
      for (int mt = 0; mt < 2; ++mt)
#pragma unroll
        for (int nt = 0; nt < 4; ++nt)
          acc[mt][nt] = __builtin_amdgcn_mfma_f32_16x16x32_bf16(af[mt], bfr[nt], acc[mt][nt], 0, 0, 0);
    }
  }
#pragma unroll
  for (int mt = 0; mt < 2; ++mt)
#pragma unroll
    for (int nt = 0; nt < 4; ++nt) {
      int r0 = bm + wm + mt * 16 + quad * 4;
      int c  = bn + nt * 16 + li;
#pragma unroll
      for (int r = 0; r < 4; ++r)
        Cf[(size_t)(r0 + r) * LDC + c] = acc[mt][nt][r];
    }
}

// ---- qkvh V-section [B*L][1536]+1024 -> vt [(b*8+h)*64+d][4096] (per-head V^T) ----
__global__ __launch_bounds__(256) void vtrans(const unsigned short* __restrict__ qkv,
                                              unsigned short* __restrict__ vt) {
  __shared__ __align__(16) unsigned short T[64 * 72];
  const int kt = blockIdx.x;
  const int bh = blockIdx.y;
  const int b = bh >> 3, h = bh & 7;
  const int tid = threadIdx.x;
#pragma unroll
  for (int i = 0; i < 2; ++i) {
    int chunk = i * 256 + tid;
    int row = chunk >> 3, c8 = chunk & 7;
    *(uint4*)(T + row * 72 + c8 * 8) =
        *(const uint4*)(qkv + (size_t)(b * 4096 + kt * 64 + row) * 1536 + 1024 + h * 64 + c8 * 8);
  }
  __syncthreads();
#pragma unroll
  for (int i = 0; i < 2; ++i) {
    int chunk = i * 256 + tid;
    int dr = chunk >> 3, c8 = chunk & 7;
    u16x8 v;
#pragma unroll
    for (int j = 0; j < 8; ++j) v[j] = T[(c8 * 8 + j) * 72 + dr];
    *(u16x8*)(vt + (size_t)(bh * 64 + dr) * 4096 + kt * 64 + c8 * 8) = v;
  }
}

// ---- split-K flash attention, S^T form, no-max softmax, l-via-ones-MFMA. ----
// block = (qt:128q, h, b*2+half); 8 waves x 16q; each block does 32 key-tiles.
// Writes UNNORMALIZED fp32 O partial + per-query l. qh pre-scaled by 1/8*log2(e).
__global__ __launch_bounds__(512) void attn(const unsigned short* __restrict__ qkv,
                                            const unsigned short* __restrict__ vt,
                                            const int* __restrict__ mask,
                                            float* __restrict__ O0, float* __restrict__ O1,
                                            float* __restrict__ Lb) {
  __shared__ __align__(16) unsigned short Kbuf[2][64 * 64];
  __shared__ __align__(16) unsigned short Vbuf[2][64 * 64];
  __shared__ __align__(16) unsigned short Psh[8][16 * 72];
  __shared__ __align__(16) unsigned short MskBits[256];
  const int qt = blockIdx.x, h = blockIdx.y, z = blockIdx.z;
  const int b = z >> 1, half = z & 1;
  const int t0 = half * 32;
  const int tid = threadIdx.x;
  const int wid = tid >> 6, lane = tid & 63, quad = lane >> 4, li = lane & 15;
  const size_t tok0 = (size_t)b * 4096;

  if (tid < 256) {
    const int4* mp = (const int4*)(mask + b * 4096 + tid * 16);
    unsigned int bits = 0;
#pragma unroll
    for (int j = 0; j < 4; ++j) {
      int4 m4 = mp[j];
      bits |= (m4.x ? 1u : 0u) << (j * 4 + 0);
      bits |= (m4.y ? 1u : 0u) << (j * 4 + 1);
      bits |= (m4.z ? 1u : 0u) << (j * 4 + 2);
      bits |= (m4.w ? 1u : 0u) << (j * 4 + 3);
    }
    MskBits[tid] = (unsigned short)bits;
  }

  const unsigned short* qp = qkv + (tok0 + qt * 128 + wid * 16 + li) * 1536 + h * 64;
  bf16x8 bq0 = *(const bf16x8*)(qp + quad * 8);
  bf16x8 bq1 = *(const bf16x8*)(qp + 32 + quad * 8);

  const unsigned short* kbase = qkv + tok0 * 1536 + 512 + h * 64;
  const unsigned short* vbase = vt + (size_t)(b * 8 + h) * 64 * 4096;
  const int wk = wid & 3;
  const int lam0 = wk * 128 + lane, lam1 = lam0 + 64;
  const int r0 = lam0 >> 3, c0 = (lam0 & 7) ^ (r0 & 7);
  const int r1 = lam1 >> 3, c1 = (lam1 & 7) ^ (r1 & 7);
  const unsigned short *g0, *g1;
  size_t kstride;
  unsigned short *lb0, *lb1;
  if (wid < 4) {
    g0 = kbase + (size_t)(t0 * 64 + r0) * 1536 + c0 * 8;
    g1 = kbase + (size_t)(t0 * 64 + r1) * 1536 + c1 * 8;
    kstride = (size_t)64 * 1536;
    lb0 = &Kbuf[0][0]; lb1 = &Kbuf[1][0];
  } else {
    g0 = vbase + (size_t)r0 * 4096 + t0 * 64 + c0 * 8;
    g1 = vbase + (size_t)r1 * 4096 + t0 * 64 + c1 * 8;
    kstride = 64;
    lb0 = &Vbuf[0][0]; lb1 = &Vbuf[1][0];
  }
  const int o0 = lam0 * 8, o1 = lam1 * 8;

  gl2lds16(g0, lb0 + o0);
  gl2lds16(g1, lb0 + o1);
  g0 += kstride; g1 += kstride;

  f32x4 accO[4] = {};
  f32x4 accL = {};
  bf16x8 bones;
#pragma unroll
  for (int j = 0; j < 8; ++j) bones[j] = (short)0x3F80;  // bf16 1.0
  unsigned short* Pw = &Psh[wid][0];
  const int sw = li & 7;

  for (int tt = 0; tt < 32; ++tt) {
    const int t = t0 + tt;
    __syncthreads();
    if (tt < 31) {
      unsigned short* lb = ((tt + 1) & 1) ? lb1 : lb0;
      gl2lds16(g0, lb + o0);
      gl2lds16(g1, lb + o1);
      g0 += kstride; g1 += kstride;
    }
    const unsigned short* Ks = &Kbuf[tt & 1][0];
    const unsigned short* Vs = &Vbuf[tt & 1][0];

    // S^T = K Q^T: lane = query li; keys kb*16 + quad*4 + r
    f32x4 s[4];
#pragma unroll
    for (int kb = 0; kb < 4; ++kb) {
      const unsigned short* kr = Ks + (kb * 16 + li) * 64;
      bf16x8 ak0 = *(const bf16x8*)(kr + ((quad ^ sw) * 8));
      bf16x8 ak1 = *(const bf16x8*)(kr + (((4 + quad) ^ sw) * 8));
      f32x4 zv = {};
      zv = __builtin_amdgcn_mfma_f32_16x16x32_bf16(ak0, bq0, zv, 0, 0, 0);
      zv = __builtin_amdgcn_mfma_f32_16x16x32_bf16(ak1, bq1, zv, 0, 0, 0);
      s[kb] = zv;
    }
    unsigned long long mbits = *(const unsigned long long*)(MskBits + t * 4);
    if (mbits != ~0ull) {
#pragma unroll
      for (int kb = 0; kb < 4; ++kb)
#pragma unroll
        for (int r = 0; r < 4; ++r) {
          int key = kb * 16 + quad * 4 + r;
          if (!((mbits >> key) & 1ull)) s[kb][r] = -1e30f;
        }
    }
    // p = exp2(s); pack to bf16 P (l comes from ones-MFMA)
#pragma unroll
    for (int kb = 0; kb < 4; ++kb) {
#pragma unroll
      for (int r = 0; r < 4; ++r) s[kb][r] = __builtin_amdgcn_exp2f(s[kb][r]);
      uint2 pk;
      pk.x = pk2bf(s[kb][0], s[kb][1]);
      pk.y = pk2bf(s[kb][2], s[kb][3]);
      *(uint2*)(Pw + li * 72 + kb * 16 + quad * 4) = pk;
    }
    // O += P V ; l += P * ones
    bf16x8 p0 = *(const bf16x8*)(Pw + li * 72 + quad * 8);
    bf16x8 p1 = *(const bf16x8*)(Pw + li * 72 + 32 + quad * 8);
#pragma unroll
    for (int dc = 0; dc < 4; ++dc) {
      const unsigned short* vr = Vs + (dc * 16 + li) * 64;
      bf16x8 bv0 = *(const bf16x8*)(vr + ((quad ^ sw) * 8));
      bf16x8 bv1 = *(const bf16x8*)(vr + (((4 + quad) ^ sw) * 8));
      accO[dc] = __builtin_amdgcn_mfma_f32_16x16x32_bf16(p0, bv0, accO[dc], 0, 0, 0);
      accO[dc] = __builtin_amdgcn_mfma_f32_16x16x32_bf16(p1, bv1, accO[dc], 0, 0, 0);
    }
    accL = __builtin_amdgcn_mfma_f32_16x16x32_bf16(p0, bones, accL, 0, 0, 0);
    accL = __builtin_amdgcn_mfma_f32_16x16x32_bf16(p1, bones, accL, 0, 0, 0);
  }
  // epilogue: write unnormalized fp32 partial + l (accL rows align with accO rows)
  float* Oh = half ? O1 : O0;
  const size_t rq = tok0 + qt * 128 + wid * 16 + quad * 4;
#pragma unroll
  for (int dc = 0; dc < 4; ++dc) {
    size_t col = h * 64 + dc * 16 + li;
#pragma unroll
    for (int r = 0; r < 4; ++r)
      Oh[(rq + r) * 512 + col] = accO[dc][r];
  }
  if (li == 0) {
#pragma unroll
    for (int r = 0; r < 4; ++r)
      Lb[((size_t)half * 8192 + rq + r) * 8 + h] = accL[r];
  }
}

// ---- combine: ob = (O0+O1)/(l0+l1), bf16 ----
__global__ __launch_bounds__(256) void cmb(const float* __restrict__ O0, const float* __restrict__ O1,
                                           const float* __restrict__ Lb,
                                           unsigned short* __restrict__ ob) {
  int idx = (blockIdx.x * 256 + threadIdx.x) * 4;   // over 8192*512
  int tok = idx >> 9, h = (idx >> 6) & 7;
  float inv = 1.f / (Lb[(size_t)tok * 8 + h] + Lb[(size_t)(8192 + tok) * 8 + h]);
  float4 a = *(const float4*)(O0 + idx);
  float4 b = *(const float4*)(O1 + idx);
  uint2 pk;
  pk.x = pk2bf((a.x + b.x) * inv, (a.y + b.y) * inv);
  pk.y = pk2bf((a.z + b.z) * inv, (a.w + b.w) * inv);
  *(uint2*)(ob + idx) = pk;
}

extern "C" void kernel_launch(void* const* d_in, const int* in_sizes, int n_in,
                              void* d_out, int out_size, void* d_ws, size_t ws_size,
                              hipStream_t stream) {
  const float* q  = (const float*)d_in[0];
  const float* k  = (const float*)d_in[1];
  const float* v  = (const float*)d_in[2];
  const int* mask = (const int*)d_in[3];
  const float* Wq = (const float*)d_in[4];
  const float* Wk = (const float*)d_in[5];
  const float* Wv = (const float*)d_in[6];
  const float* Wo = (const float*)d_in[7];
  float* out = (float*)d_out;

  char* ws = (char*)d_ws;
  const size_t MB = 1024 * 1024;
  // Arena (66.5 MB total), time-sliced aliasing:
  //  [0,24M)   xbf (packed bf16 QKV inputs)  ->  O0 fp32 [0,16M) + (vt/ob at [16,24M))
  //  [16,24M)  vt (after gemm_qkv)           ->  ob (after attn, written by cmb)
  //  [24,48M)  qkvh (proj output)
  //  [48,50M)  wAll (4 transposed weights)
  //  [50,66M)  O1 fp32
  //  [66M,..)  Lb (2*8192*8 fp32)
  unsigned short* xbf  = (unsigned short*)(ws);
  unsigned short* vtb  = (unsigned short*)(ws + 16 * MB);
  unsigned short* obb  = (unsigned short*)(ws + 16 * MB);
  unsigned short* qkvh = (unsigned short*)(ws + 24 * MB);
  unsigned short* wAll = (unsigned short*)(ws + 48 * MB);
  unsigned short* woT  = wAll + (size_t)3 * 512 * 512;
  float* O0f = (float*)(ws);
  float* O1f = (float*)(ws + 50 * MB);
  float* Lb  = (float*)(ws + 66 * MB);

  dim3 cg(2048, 3);
  cvt3<<<cg, 256, 0, stream>>>(q, k, v, xbf);
  dim3 wg(8, 8, 4);
  wtrans4<<<wg, 256, 0, stream>>>(Wq, Wk, Wv, Wo, wAll);
  const float qscale = 0.125f * 1.44269504f;  // 1/sqrt(64) * log2(e)
  dim3 gq(64, 12);
  gemm_qkv<<<gq, 256, 0, stream>>>(xbf, wAll, qkvh, qscale);
  dim3 vg(64, 16);
  vtrans<<<vg, 256, 0, stream>>>(qkvh, vtb);
  dim3 ag(32, 8, 4);
  attn<<<ag, 512, 0, stream>>>(qkvh, vtb, mask, O0f, O1f, Lb);
  cmb<<<4096, 256, 0, stream>>>(O0f, O1f, Lb, obb);
  dim3 go(64, 8);
  gemm_o<<<go, 256, 0, stream>>>(obb, woT, out);
}